// Round 5
// baseline (272.905 us; speedup 1.0000x reference)
//
#include <hip/hip_runtime.h>

#define NB 4
#define NC 64
#define MID 16
#define NH 4
#define KS 7
#define PAD 3
#define HH 128
#define WW 128
#define TILE 16
#define HALO (TILE + KS - 1)   /* 22 */
#define PLANE (HH * WW)

// ---------------- QKV 1x1 conv ----------------
// One thread per pixel; blockIdx.y selects which 16-output slice (o0..o0+15)
// of each of Q/K/V this thread computes. x channels held fully in registers.
__global__ __launch_bounds__(256) void qkv_kernel(
    const float* __restrict__ x,
    const float* __restrict__ Wq, const float* __restrict__ bq,
    const float* __restrict__ Wk, const float* __restrict__ bk,
    const float* __restrict__ Wv, const float* __restrict__ bv,
    float* __restrict__ Qm, float* __restrict__ Km, float* __restrict__ Vm)
{
    const int pix = blockIdx.x * 256 + threadIdx.x;   // 0 .. NB*PLANE-1
    const int b   = pix / PLANE;
    const int hw  = pix - b * PLANE;
    const int o0  = blockIdx.y * 16;

    const float* xp = x + (size_t)b * NC * PLANE + hw;
    float xr[NC];
    #pragma unroll
    for (int c = 0; c < NC; ++c) xr[c] = xp[(size_t)c * PLANE];

    const size_t obase = (size_t)b * NC * PLANE + hw;
    for (int j = 0; j < 16; ++j) {
        const int o = o0 + j;
        float aq = bq[o], ak = bk[o], av = bv[o];
        const float* wq = Wq + o * NC;
        const float* wk = Wk + o * NC;
        const float* wv = Wv + o * NC;
        #pragma unroll
        for (int c = 0; c < NC; ++c) {
            aq = fmaf(wq[c], xr[c], aq);
            ak = fmaf(wk[c], xr[c], ak);
            av = fmaf(wv[c], xr[c], av);
        }
        Qm[obase + (size_t)o * PLANE] = aq;
        Km[obase + (size_t)o * PLANE] = ak;
        Vm[obase + (size_t)o * PLANE] = av;
    }
}

// ---------------- neighborhood attention ----------------
// One block per (b, g, 16x16 spatial tile). K/V halo (22x22x16) staged in LDS,
// zero-filled out of bounds (matches zero-padded unfold: OOB taps contribute
// score 0 and V 0, but DO enter the softmax denominator).
__global__ __launch_bounds__(256) void attn_kernel(
    const float* __restrict__ x,
    const float* __restrict__ Qm, const float* __restrict__ Km,
    const float* __restrict__ Vm, float* __restrict__ out)
{
    __shared__ float Kt[MID][HALO][HALO + 1];
    __shared__ float Vt[MID][HALO][HALO + 1];

    int blk = blockIdx.x;
    const int tx0 = (blk & 7) * TILE; blk >>= 3;
    const int ty0 = (blk & 7) * TILE; blk >>= 3;
    const int g   = blk & 3;
    const int b   = blk >> 2;

    const float* Kbase = Km + ((size_t)b * NC + g * MID) * PLANE;
    const float* Vbase = Vm + ((size_t)b * NC + g * MID) * PLANE;

    for (int i = threadIdx.x; i < MID * HALO * HALO; i += 256) {
        const int xx = i % HALO;
        const int t  = i / HALO;
        const int yy = t % HALO;
        const int c  = t / HALO;
        const int h  = ty0 + yy - PAD;
        const int w  = tx0 + xx - PAD;
        const bool in = (h >= 0) & (h < HH) & (w >= 0) & (w < WW);
        const size_t gidx = (size_t)c * PLANE + (size_t)h * WW + w;
        Kt[c][yy][xx] = in ? Kbase[gidx] : 0.f;
        Vt[c][yy][xx] = in ? Vbase[gidx] : 0.f;
    }
    __syncthreads();

    const int tx = threadIdx.x & (TILE - 1);
    const int ty = threadIdx.x >> 4;
    const size_t pbase = ((size_t)b * NC + g * MID) * PLANE
                       + (size_t)(ty0 + ty) * WW + (tx0 + tx);

    float q[MID];
    #pragma unroll
    for (int c = 0; c < MID; ++c) q[c] = Qm[pbase + (size_t)c * PLANE];

    float l = 0.f;
    float acc[MID];
    #pragma unroll
    for (int c = 0; c < MID; ++c) acc[c] = 0.f;

    for (int kh = 0; kh < KS; ++kh) {
        #pragma unroll
        for (int kw = 0; kw < KS; ++kw) {
            const int yy = ty + kh, xx = tx + kw;
            float s = 0.f;
            #pragma unroll
            for (int c = 0; c < MID; ++c) s = fmaf(q[c], Kt[c][yy][xx], s);
            const float wgt = __expf(s);   // scores bounded ~|25| -> safe in fp32
            l += wgt;
            #pragma unroll
            for (int c = 0; c < MID; ++c) acc[c] = fmaf(wgt, Vt[c][yy][xx], acc[c]);
        }
    }

    const float inv = 1.f / l;
    #pragma unroll
    for (int c = 0; c < MID; ++c) {
        const size_t idx = pbase + (size_t)c * PLANE;
        out[idx] = x[idx] + acc[c] * inv;
    }
}

extern "C" void kernel_launch(void* const* d_in, const int* in_sizes, int n_in,
                              void* d_out, int out_size, void* d_ws, size_t ws_size,
                              hipStream_t stream) {
    const float* x  = (const float*)d_in[0];
    const float* Wq = (const float*)d_in[1];
    const float* bq = (const float*)d_in[2];
    const float* Wk = (const float*)d_in[3];
    const float* bk = (const float*)d_in[4];
    const float* Wv = (const float*)d_in[5];
    const float* bv = (const float*)d_in[6];
    float* out = (float*)d_out;

    const size_t map_elems = (size_t)NB * NC * PLANE;   // 4*64*16384
    float* Qm = (float*)d_ws;
    float* Km = Qm + map_elems;
    float* Vm = Km + map_elems;
    // needs 3 * 16.8 MB = 50.4 MB of workspace

    dim3 g1(NB * PLANE / 256, 4);
    qkv_kernel<<<g1, 256, 0, stream>>>(x, Wq, bq, Wk, bk, Wv, bv, Qm, Km, Vm);

    const int nblk = NB * NH * (HH / TILE) * (WW / TILE);   // 1024
    attn_kernel<<<nblk, 256, 0, stream>>>(x, Qm, Km, Vm, out);
}